// Round 3
// baseline (596.735 us; speedup 1.0000x reference)
//
#include <hip/hip_runtime.h>

#define S_LEN 2048

typedef __attribute__((ext_vector_type(8))) short bf16x8;
typedef __attribute__((ext_vector_type(4))) float f32x4;
typedef unsigned long long u64;
typedef unsigned int u32;
typedef unsigned short u16;

#define MFMA16 __builtin_amdgcn_mfma_f32_16x16x32_bf16

__device__ __forceinline__ u32 asu(float f) { union { float f; u32 u; } v; v.f = f; return v.u; }

// pack 2 floats -> bf16 pair (a -> low16, b -> high16), round-half-up via +0x8000 then v_perm.
// 3 VALU ops for 2 values; bias vs RNE is <= 1 ulp and irrelevant at our error budget.
__device__ __forceinline__ u32 pkbf(float a, float b) {
  return __builtin_amdgcn_perm(asu(b) + 0x8000u, asu(a) + 0x8000u, 0x07060302u);
}

// Load one 16B MFMA fragment from an XOR-swizzled LDS tile (nblk 16B-blocks per row).
__device__ __forceinline__ bf16x8 ldfrag(const u16* base, int row, int blk, int nblk) {
  const int xm = nblk - 1;
  const char* p = (const char*)base + (((row * nblk) + (blk ^ (row & xm))) << 4);
  return *(const bf16x8*)p;
}

// Swizzled u64 slot for a (row, c4) pair in a 128x64 bf16 tile (8 blocks/row).
__device__ __forceinline__ u64* qkaddr(u16* dst, int row, int c4) {
  const int cb = c4 >> 1;
  return (u64*)((char*)dst + ((((row << 3) + (cb ^ (row & 7))) << 4) + ((c4 & 1) << 3)));
}

// One block = one (b*h, 128-row q-tile). 256 threads = 4 waves.
// Phase 1: lse[q] = log(sum_k exp(q.k/8))    (fixed max 0 — scores O(1), no overflow)
// Phase 2: W = mask ? s - lse : -1e9 (bf16), O^T = V^T * W^T, out[b][q][h*64+d].
// K/V/mask for tile kt+1 are prefetched into registers during tile kt's compute.
__global__ __launch_bounds__(256, 2) void attn_kernel(
    const float* __restrict__ gq, const float* __restrict__ gk,
    const float* __restrict__ gv, const int* __restrict__ gmask,
    float* __restrict__ gout) {
  __shared__ __align__(16) u16 sQ[128 * 64];
  __shared__ __align__(16) u16 sK[128 * 64];
  __shared__ __align__(16) u16 sV[64 * 128];   // sRed aliases (phase-1 tail only)
  __shared__ __align__(16) u16 sW[128 * 128];
  float* sRed = (float*)sV;

  const int t = threadIdx.x;
  const int wv = t >> 6;
  const int lane = t & 63;
  const int c = lane & 15;
  const int quad = lane >> 4;
  const int r0 = t >> 4, c4 = t & 15;

  const int bx = blockIdx.x;
  const int bh = bx & 63;
  const int qt = bx >> 6;
  const int q0 = qt << 7;

  const float* qg = gq + ((size_t)bh << 17) + ((size_t)q0 << 6);
  const float* kg = gk + ((size_t)bh << 17);
  const float* vg = gv + ((size_t)bh << 17);

  // ---- stage Q once (fold 1/sqrt(64) = 0.125 into Q) ----
#pragma unroll
  for (int i = 0; i < 8; ++i) {
    const int row = r0 + (i << 4);
    const float4 f = *(const float4*)(qg + ((size_t)row << 6) + (c4 << 2));
    const u32 lo = pkbf(f.x * 0.125f, f.y * 0.125f);
    const u32 hi = pkbf(f.z * 0.125f, f.w * 0.125f);
    *qkaddr(sQ, row, c4) = (u64)lo | ((u64)hi << 32);
  }

  // ---- prefetch K tile 0 ----
  float4 krg[8];
#pragma unroll
  for (int i = 0; i < 8; ++i)
    krg[i] = *(const float4*)(kg + ((size_t)(r0 + (i << 4)) << 6) + (c4 << 2));

  float lacc[8];
#pragma unroll
  for (int i = 0; i < 8; ++i) lacc[i] = 0.f;

  // ---------------- phase 1: logsumexp ----------------
  for (int kt = 0; kt < 16; ++kt) {
    // convert prefetched K regs -> sK
#pragma unroll
    for (int i = 0; i < 8; ++i) {
      const int row = r0 + (i << 4);
      const u32 lo = pkbf(krg[i].x, krg[i].y);
      const u32 hi = pkbf(krg[i].z, krg[i].w);
      *qkaddr(sK, row, c4) = (u64)lo | ((u64)hi << 32);
    }
    __syncthreads();
    // issue next K tile (wraps to tile 0 at kt=15 -> feeds phase 2's first tile)
    {
      const float* kn = kg + ((size_t)(((kt + 1) & 15) << 7) << 6);
#pragma unroll
      for (int i = 0; i < 8; ++i)
        krg[i] = *(const float4*)(kn + ((size_t)(r0 + (i << 4)) << 6) + (c4 << 2));
    }
    bf16x8 kf[2][2];
#pragma unroll
    for (int tr = 0; tr < 2; ++tr)
#pragma unroll
      for (int ks = 0; ks < 2; ++ks)
        kf[tr][ks] = ldfrag(sK, (wv << 5) + (tr << 4) + c, (ks << 2) + quad, 8);
#pragma unroll
    for (int tn = 0; tn < 8; ++tn) {
      const bf16x8 qf0 = ldfrag(sQ, (tn << 4) + c, quad, 8);
      const bf16x8 qf1 = ldfrag(sQ, (tn << 4) + c, 4 + quad, 8);
#pragma unroll
      for (int tr = 0; tr < 2; ++tr) {
        f32x4 acc = {0.f, 0.f, 0.f, 0.f};
        acc = MFMA16(kf[tr][0], qf0, acc, 0, 0, 0);
        acc = MFMA16(kf[tr][1], qf1, acc, 0, 0, 0);
        lacc[tn] += __expf(acc[0]) + __expf(acc[1]) + __expf(acc[2]) + __expf(acc[3]);
      }
    }
    __syncthreads();
  }

  // ---- prefetch phase-2 tile 0: V and mask (K tile 0 already in krg via wrap) ----
  float4 vrg[8];
#pragma unroll
  for (int i = 0; i < 4; ++i) {
    const int kr = (r0 << 1) + (i << 5);
    vrg[2 * i] = *(const float4*)(vg + ((size_t)kr << 6) + (c4 << 2));
    vrg[2 * i + 1] = *(const float4*)(vg + ((size_t)(kr + 1) << 6) + (c4 << 2));
  }
  int4 mrg[16];
#pragma unroll
  for (int tn = 0; tn < 8; ++tn)
#pragma unroll
    for (int tr = 0; tr < 2; ++tr)
      mrg[tn * 2 + tr] = *(const int4*)(gmask + (size_t)(q0 + (tn << 4) + c) * S_LEN +
                                        (wv << 5) + (tr << 4) + (quad << 2));

  // lse reduction (overlaps the prefetch latency above)
#pragma unroll
  for (int tn = 0; tn < 8; ++tn) {
    float v = lacc[tn];
    v += __shfl_xor(v, 16, 64);
    v += __shfl_xor(v, 32, 64);
    if (quad == 0) sRed[(wv << 7) + (tn << 4) + c] = v;
  }
  __syncthreads();
  float lq[8];
#pragma unroll
  for (int tn = 0; tn < 8; ++tn) {
    const int i = (tn << 4) + c;
    lq[tn] = __logf(sRed[i] + sRed[128 + i] + sRed[256 + i] + sRed[384 + i]);
  }
  __syncthreads();  // sRed (=sV) dead

  // ---------------- phase 2 ----------------
  f32x4 oacc[4][2];
#pragma unroll
  for (int mt = 0; mt < 4; ++mt)
#pragma unroll
    for (int j = 0; j < 2; ++j) {
      f32x4 z = {0.f, 0.f, 0.f, 0.f};
      oacc[mt][j] = z;
    }

  for (int kt = 0; kt < 16; ++kt) {
    // convert prefetched K,V regs -> sK, sV
#pragma unroll
    for (int i = 0; i < 8; ++i) {
      const int row = r0 + (i << 4);
      const u32 lo = pkbf(krg[i].x, krg[i].y);
      const u32 hi = pkbf(krg[i].z, krg[i].w);
      *qkaddr(sK, row, c4) = (u64)lo | ((u64)hi << 32);
    }
#pragma unroll
    for (int i = 0; i < 4; ++i) {
      const int kr = (r0 << 1) + (i << 5);
      const float4 a = vrg[2 * i], b2 = vrg[2 * i + 1];
      const float av[4] = {a.x, a.y, a.z, a.w}, bv[4] = {b2.x, b2.y, b2.z, b2.w};
      const int cb = kr >> 3;
#pragma unroll
      for (int j = 0; j < 4; ++j) {
        const int d = (c4 << 2) + j;
        *(u32*)((char*)sV + ((((d << 4) + (cb ^ (d & 15))) << 4) + ((kr & 7) << 1))) =
            pkbf(av[j], bv[j]);
      }
    }
    __syncthreads();
    // issue next K,V tiles (latency hidden by QK + W + PV below)
    const int ktn = (kt + 1) & 15;
    {
      const float* kn = kg + ((size_t)(ktn << 7) << 6);
      const float* vn = vg + ((size_t)(ktn << 7) << 6);
#pragma unroll
      for (int i = 0; i < 8; ++i)
        krg[i] = *(const float4*)(kn + ((size_t)(r0 + (i << 4)) << 6) + (c4 << 2));
#pragma unroll
      for (int i = 0; i < 4; ++i) {
        const int kr = (r0 << 1) + (i << 5);
        vrg[2 * i] = *(const float4*)(vn + ((size_t)kr << 6) + (c4 << 2));
        vrg[2 * i + 1] = *(const float4*)(vn + ((size_t)(kr + 1) << 6) + (c4 << 2));
      }
    }
    // QK + W formation (mask comes from prefetched mrg registers)
    bf16x8 kf[2][2];
#pragma unroll
    for (int tr = 0; tr < 2; ++tr)
#pragma unroll
      for (int ks = 0; ks < 2; ++ks)
        kf[tr][ks] = ldfrag(sK, (wv << 5) + (tr << 4) + c, (ks << 2) + quad, 8);
#pragma unroll
    for (int tn = 0; tn < 8; ++tn) {
      const bf16x8 qf0 = ldfrag(sQ, (tn << 4) + c, quad, 8);
      const bf16x8 qf1 = ldfrag(sQ, (tn << 4) + c, 4 + quad, 8);
      const float l = lq[tn];
#pragma unroll
      for (int tr = 0; tr < 2; ++tr) {
        f32x4 acc = {0.f, 0.f, 0.f, 0.f};
        acc = MFMA16(kf[tr][0], qf0, acc, 0, 0, 0);
        acc = MFMA16(kf[tr][1], qf1, acc, 0, 0, 0);
        const int4 mm = mrg[tn * 2 + tr];
        const float w0 = mm.x ? acc[0] - l : -1e9f;
        const float w1 = mm.y ? acc[1] - l : -1e9f;
        const float w2 = mm.z ? acc[2] - l : -1e9f;
        const float w3 = mm.w ? acc[3] - l : -1e9f;
        const u32 lo = pkbf(w0, w1), hi = pkbf(w2, w3);
        const int kc = (wv << 5) + (tr << 4) + (quad << 2);
        const int row = (tn << 4) + c;
        const int cb = kc >> 3;
        *(u64*)((char*)sW + ((((row << 4) + (cb ^ (row & 15))) << 4) + ((quad & 1) << 3))) =
            (u64)lo | ((u64)hi << 32);
      }
    }
    // issue next mask tile (mrg dead; latency hidden by PV + next convert)
    {
      const int mk0 = ktn << 7;
#pragma unroll
      for (int tn = 0; tn < 8; ++tn)
#pragma unroll
        for (int tr = 0; tr < 2; ++tr)
          mrg[tn * 2 + tr] = *(const int4*)(gmask + (size_t)(q0 + (tn << 4) + c) * S_LEN +
                                            mk0 + (wv << 5) + (tr << 4) + (quad << 2));
    }
    __syncthreads();
    // PV: O^T[d][q] += V^T * W^T
#pragma unroll
    for (int ks = 0; ks < 4; ++ks) {
      const bf16x8 b0 = ldfrag(sW, ((wv << 1) << 4) + c, (ks << 2) + quad, 16);
      const bf16x8 b1 = ldfrag(sW, (((wv << 1) + 1) << 4) + c, (ks << 2) + quad, 16);
#pragma unroll
      for (int mt = 0; mt < 4; ++mt) {
        const bf16x8 a = ldfrag(sV, (mt << 4) + c, (ks << 2) + quad, 16);
        oacc[mt][0] = MFMA16(a, b0, oacc[mt][0], 0, 0, 0);
        oacc[mt][1] = MFMA16(a, b1, oacc[mt][1], 0, 0, 0);
      }
    }
    __syncthreads();
  }

  // epilogue: O^T C-layout: col(q) = c + 16*tn, row(d) = 16*mt + 4*quad + reg
  const int b = bh >> 4, h = bh & 15;
#pragma unroll
  for (int mt = 0; mt < 4; ++mt) {
#pragma unroll
    for (int tnn = 0; tnn < 2; ++tnn) {
      const int tn = (wv << 1) + tnn;
      float4 o;
      o.x = oacc[mt][tnn][0]; o.y = oacc[mt][tnn][1];
      o.z = oacc[mt][tnn][2]; o.w = oacc[mt][tnn][3];
      const size_t off = ((size_t)b * S_LEN + (size_t)(q0 + (tn << 4) + c)) * 1024
                       + (h << 6) + (mt << 4) + (quad << 2);
      *(float4*)(gout + off) = o;
    }
  }
}

extern "C" void kernel_launch(void* const* d_in, const int* in_sizes, int n_in,
                              void* d_out, int out_size, void* d_ws, size_t ws_size,
                              hipStream_t stream) {
  const float* q = (const float*)d_in[0];
  const float* k = (const float*)d_in[1];
  const float* v = (const float*)d_in[2];
  const int* mask = (const int*)d_in[3];
  (void)in_sizes; (void)n_in; (void)out_size; (void)d_ws; (void)ws_size;
  attn_kernel<<<dim3(1024), dim3(256), 0, stream>>>(q, k, v, mask, (float*)d_out);
}

// Round 4
// 425.646 us; speedup vs baseline: 1.4020x; 1.4020x over previous
//
#include <hip/hip_runtime.h>

#define S_LEN 2048

typedef __attribute__((ext_vector_type(8))) short bf16x8;
typedef __attribute__((ext_vector_type(4))) float f32x4;
typedef unsigned long long u64;
typedef unsigned int u32;
typedef unsigned short u16;

#define MFMA16 __builtin_amdgcn_mfma_f32_16x16x32_bf16

__device__ __forceinline__ u32 asu(float f) { union { float f; u32 u; } v; v.f = f; return v.u; }

// pack 2 floats -> bf16 pair (a=low16, b=high16), round-half-up via +0x8000 + v_perm.
__device__ __forceinline__ u32 pkbf(float a, float b) {
  return __builtin_amdgcn_perm(asu(b) + 0x8000u, asu(a) + 0x8000u, 0x07060302u);
}

// 64x64 bf16 tile, 128B rows, 8 x 16B blocks/row, block swizzled by xor(row&7).
__device__ __forceinline__ u64* qkaddr(u16* dst, int row, int c4) {
  const int cb = c4 >> 1;
  return (u64*)((char*)dst + ((((row << 3) + (cb ^ (row & 7))) << 4) + ((c4 & 1) << 3)));
}
__device__ __forceinline__ bf16x8 ldfrag(const u16* base, int row, int blk) {
  const char* p = (const char*)base + (((row << 3) + (blk ^ (row & 7))) << 4);
  return *(const bf16x8*)p;
}
// padded tile: 144B row stride (64 bf16 + 8 pad), no swizzle (pad de-conflicts banks).
__device__ __forceinline__ bf16x8 ldpad(const u16* base, int row, int blk) {
  const char* p = (const char*)base + row * 144 + (blk << 4);
  return *(const bf16x8*)p;
}

// One block = one (b*h, 64-row q-tile); 2048 blocks, 256 threads (4 waves).
// Single pass over K:  out = A + (1e9 - lse)*Bm - 1e9*Vsum
//   A  = sum_k mask*s*v      (bf16 MFMA, s = q.k/8 via QK MFMA)
//   Bm = sum_k mask*v        (mask as exact bf16 0/1)
//   Vsum[d] = sum_k v[k][d]  (fp32, accumulated during V staging)
//   lse = log sum_k exp(s)   (fixed max 0; |s|<~8 so no overflow)
// Wave wv owns q-columns 16*wv..16*wv+15 for QK output, W tiles, PV, lse, epilogue.
__global__ __launch_bounds__(256, 4) void attn_kernel(
    const float* __restrict__ gq, const float* __restrict__ gk,
    const float* __restrict__ gv, const int* __restrict__ gmask,
    float* __restrict__ gout) {
  __shared__ __align__(16) u16 sK[64 * 64];        // 8 KB, swizzled
  __shared__ __align__(16) u16 sV[64 * 72];        // 9 KB, V^T (d-major), padded rows
  __shared__ __align__(16) u16 sW[2 * 64 * 72];    // 18 KB: W1 (mask*s), W2 (mask); Q staged here once

  const int t = threadIdx.x;
  const int wv = t >> 6;
  const int lane = t & 63;
  const int c = lane & 15;
  const int quad = lane >> 4;
  const int r0 = t >> 4, c4 = t & 15;

  const int bx = blockIdx.x;
  const int bh = bx & 63;            // consecutive blocks share the q-tile -> mask L3 locality
  const int q0 = (bx >> 6) << 6;

  const float* qg = gq + ((size_t)bh << 17) + ((size_t)q0 << 6);
  const float* kg = gk + ((size_t)bh << 17);
  const float* vg = gv + ((size_t)bh << 17);

  // ---- stage Q once (scaled by 1/8) into sW region, swizzled layout ----
  u16* sQs = sW;
#pragma unroll
  for (int i = 0; i < 4; ++i) {
    const int row = r0 + (i << 4);
    const float4 f = *(const float4*)(qg + ((size_t)row << 6) + (c4 << 2));
    const u32 lo = pkbf(f.x * 0.125f, f.y * 0.125f);
    const u32 hi = pkbf(f.z * 0.125f, f.w * 0.125f);
    *qkaddr(sQs, row, c4) = (u64)lo | ((u64)hi << 32);
  }
  __syncthreads();
  // Q fragments register-resident (wave's own q-tile): qf[ks]
  bf16x8 qf[2];
#pragma unroll
  for (int ks = 0; ks < 2; ++ks)
    qf[ks] = ldfrag(sQs, (wv << 4) + c, (ks << 2) + quad);
  // NOTE: sW gets overwritten only after the first stage-barrier below.

  f32x4 accA[4], accB[4];
#pragma unroll
  for (int mt = 0; mt < 4; ++mt) {
    f32x4 z = {0.f, 0.f, 0.f, 0.f};
    accA[mt] = z; accB[mt] = z;
  }
  float vs[4] = {0.f, 0.f, 0.f, 0.f};
  float lacc = 0.f;

  u16* sW1 = sW;
  u16* sW2 = sW + 64 * 72;

  for (int kt = 0; kt < 32; ++kt) {
    const int k0 = kt << 6;
    // ---- stage K (swizzled) ----
#pragma unroll
    for (int i = 0; i < 4; ++i) {
      const int row = r0 + (i << 4);
      const float4 f = *(const float4*)(kg + ((size_t)(k0 + row) << 6) + (c4 << 2));
      const u32 lo = pkbf(f.x, f.y);
      const u32 hi = pkbf(f.z, f.w);
      *qkaddr(sK, row, c4) = (u64)lo | ((u64)hi << 32);
    }
    // ---- stage V^T (padded) + fp32 Vsum partials ----
    {
      float4 vr[4];
#pragma unroll
      for (int i = 0; i < 4; ++i)
        vr[i] = *(const float4*)(vg + ((size_t)(k0 + (r0 << 2) + i) << 6) + (c4 << 2));
      const float e0[4] = {vr[0].x, vr[0].y, vr[0].z, vr[0].w};
      const float e1[4] = {vr[1].x, vr[1].y, vr[1].z, vr[1].w};
      const float e2[4] = {vr[2].x, vr[2].y, vr[2].z, vr[2].w};
      const float e3[4] = {vr[3].x, vr[3].y, vr[3].z, vr[3].w};
#pragma unroll
      for (int j = 0; j < 4; ++j) {
        vs[j] += (e0[j] + e1[j]) + (e2[j] + e3[j]);
        const u64 pk = (u64)pkbf(e0[j], e1[j]) | ((u64)pkbf(e2[j], e3[j]) << 32);
        *(u64*)((char*)sV + ((c4 << 2) + j) * 144 + (r0 << 3)) = pk;
      }
    }
    __syncthreads();
    // ---- QK (S^T = K*Q^T) + exp accumulation + W1/W2 formation ----
#pragma unroll
    for (int tr = 0; tr < 4; ++tr) {
      f32x4 acc = {0.f, 0.f, 0.f, 0.f};
      acc = MFMA16(ldfrag(sK, (tr << 4) + c, quad), qf[0], acc, 0, 0, 0);
      acc = MFMA16(ldfrag(sK, (tr << 4) + c, 4 + quad), qf[1], acc, 0, 0, 0);
      // lane holds S^T[k = k0+16tr+4quad+r][q = q0+16wv+c], r=0..3
      lacc += (__expf(acc[0]) + __expf(acc[1])) + (__expf(acc[2]) + __expf(acc[3]));
      const int4 mm = *(const int4*)(gmask + (size_t)(q0 + (wv << 4) + c) * S_LEN +
                                     k0 + (tr << 4) + (quad << 2));
      const float w0 = mm.x ? acc[0] : 0.f;
      const float w1 = mm.y ? acc[1] : 0.f;
      const float w2 = mm.z ? acc[2] : 0.f;
      const float w3 = mm.w ? acc[3] : 0.f;
      const u64 p1 = (u64)pkbf(w0, w1) | ((u64)pkbf(w2, w3) << 32);
      const u32 m_lo = (mm.x ? 0x3F80u : 0u) | (mm.y ? 0x3F800000u : 0u);
      const u32 m_hi = (mm.z ? 0x3F80u : 0u) | (mm.w ? 0x3F800000u : 0u);
      const int off = ((wv << 4) + c) * 144 + (tr << 5) + (quad << 3);
      *(u64*)((char*)sW1 + off) = p1;
      *(u64*)((char*)sW2 + off) = (u64)m_lo | ((u64)m_hi << 32);
    }
    // ---- PV: A^T += V^T * W1^T ; Bm^T += V^T * W2^T (wave-private W -> no barrier) ----
#pragma unroll
    for (int ks = 0; ks < 2; ++ks) {
      const bf16x8 bw1 = ldpad(sW1, (wv << 4) + c, (ks << 2) + quad);
      const bf16x8 bw2 = ldpad(sW2, (wv << 4) + c, (ks << 2) + quad);
#pragma unroll
      for (int mt = 0; mt < 4; ++mt) {
        const bf16x8 av = ldpad(sV, (mt << 4) + c, (ks << 2) + quad);
        accA[mt] = MFMA16(av, bw1, accA[mt], 0, 0, 0);
        accB[mt] = MFMA16(av, bw2, accB[mt], 0, 0, 0);
      }
    }
    __syncthreads();
  }

  // ---- Vsum reduction (reuse sK as fp32 scratch; last barrier already passed) ----
  float* sRed = (float*)sK;          // 16 x 64 partials
  float* vsum = (float*)sK + 1024;   // 64 totals
  {
    float4 w;
    w.x = vs[0]; w.y = vs[1]; w.z = vs[2]; w.w = vs[3];
    *(float4*)(sRed + (r0 << 6) + (c4 << 2)) = w;
  }
  __syncthreads();
  if (t < 64) {
    float s = 0.f;
#pragma unroll
    for (int r = 0; r < 16; ++r) s += sRed[(r << 6) + t];
    vsum[t] = s;
  }
  __syncthreads();

  // ---- lse (wave-local: quad butterflies only) ----
  float l = lacc;
  l += __shfl_xor(l, 16, 64);
  l += __shfl_xor(l, 32, 64);
  l = __logf(l);
  const float c1 = 1e9f - l;

  // ---- epilogue: out[b][q][h*64+d] = A + c1*Bm - 1e9*Vsum ----
  const int b = bh >> 4, h = bh & 15;
  const int qrow = q0 + (wv << 4) + c;
#pragma unroll
  for (int mt = 0; mt < 4; ++mt) {
    const f32x4 v4 = *(const f32x4*)(vsum + (mt << 4) + (quad << 2));
    float4 o;
    o.x = accA[mt][0] + c1 * accB[mt][0] - 1e9f * v4[0];
    o.y = accA[mt][1] + c1 * accB[mt][1] - 1e9f * v4[1];
    o.z = accA[mt][2] + c1 * accB[mt][2] - 1e9f * v4[2];
    o.w = accA[mt][3] + c1 * accB[mt][3] - 1e9f * v4[3];
    const size_t off = ((size_t)b * S_LEN + (size_t)qrow) * 1024 +
                       (h << 6) + (mt << 4) + (quad << 2);
    *(float4*)(gout + off) = o;
  }
}

extern "C" void kernel_launch(void* const* d_in, const int* in_sizes, int n_in,
                              void* d_out, int out_size, void* d_ws, size_t ws_size,
                              hipStream_t stream) {
  const float* q = (const float*)d_in[0];
  const float* k = (const float*)d_in[1];
  const float* v = (const float*)d_in[2];
  const int* mask = (const int*)d_in[3];
  (void)in_sizes; (void)n_in; (void)out_size; (void)d_ws; (void)ws_size;
  attn_kernel<<<dim3(2048), dim3(256), 0, stream>>>(q, k, v, mask, (float*)d_out);
}